// Round 8
// baseline (397.321 us; speedup 1.0000x reference)
//
#include <hip/hip_runtime.h>
#include <hip/hip_bf16.h>
#include <stdint.h>

#define CIN   448
#define DP    100
#define NPIX  4096
#define LNUM  4096
#define KQ    5050      // packed upper-triangle columns
#define KLIN  5150      // + 100 linear columns
#define KTOT  5184      // padded to 81*64
#define KSTEPS (KTOT / 64)
#define OUTHW 256

typedef _Float16 f16_t;
typedef _Float16 f16x8 __attribute__((ext_vector_type(8)));
typedef float    f32x4 __attribute__((ext_vector_type(4)));
typedef unsigned short u16x8 __attribute__((ext_vector_type(8)));

static __device__ __forceinline__ int tri_off(int d) { return (d * (201 - d)) >> 1; }

static __device__ __forceinline__ void unpack_tri(int k, int& d, int& e) {
    int dd = (int)((201.0f - sqrtf(40401.0f - 8.0f * (float)k)) * 0.5f);
    if (dd < 0) dd = 0;
    if (dd > 99) dd = 99;
    while (tri_off(dd + 1) <= k) ++dd;
    while (tri_off(dd) > k) --dd;
    d = dd;
    e = dd + (k - tri_off(dd));
}

static __device__ __forceinline__ unsigned f2u(float x) {
    unsigned b = __float_as_uint(x);
    return (b & 0x80000000u) ? ~b : (b | 0x80000000u);
}
static __device__ __forceinline__ float u2f(unsigned u) {
    unsigned b = (u & 0x80000000u) ? (u & 0x7FFFFFFFu) : ~u;
    return __uint_as_float(b);
}

static __device__ __forceinline__ void gload_lds16(const f16_t* g, f16_t* l) {
    __builtin_amdgcn_global_load_lds((const __attribute__((address_space(1))) unsigned*)g,
                                     (__attribute__((address_space(3))) unsigned*)l,
                                     16, 0, 0);
}

// ---------------- kernel 0: tri-unpack LUT + init per-row min ----------------
__global__ void k_lut(unsigned short* __restrict__ lut, unsigned* __restrict__ mind) {
    int k = blockIdx.x * 256 + threadIdx.x;
    if (k < KTOT) {
        int d = 0, e = 0;
        if (k < KQ) unpack_tri(k, d, e);
        lut[k] = (unsigned short)(d | (e << 8));
    }
    if (k < NPIX) mind[k] = 0xFFFFFFFFu;
}

// ---------------- kernel 1: projection, feat read ONCE (64 blocks x 64n x 100d) ----------------
__global__ __launch_bounds__(256) void k_proj(const float* __restrict__ feat, const float* __restrict__ w,
                                              const float* __restrict__ b, float* __restrict__ f) {
    __shared__ float featS[16][64];
    __shared__ float wS[DP][16];
    int n0 = blockIdx.x * 64;
    int t = threadIdx.x;
    int nn = t & 63;
    int dq = (t >> 6) * 25;            // wave-uniform d group
    float acc[25];
    #pragma unroll
    for (int j = 0; j < 25; ++j) acc[j] = 0.f;
    for (int c0 = 0; c0 < CIN; c0 += 16) {
        __syncthreads();
        for (int i = t; i < 16 * 64; i += 256) {
            int cc = i >> 6, n2 = i & 63;
            featS[cc][n2] = feat[(c0 + cc) * 4096 + n0 + n2];
        }
        for (int i = t; i < DP * 16; i += 256) {
            int d = i >> 4, cc = i & 15;
            wS[d][cc] = w[d * CIN + c0 + cc];
        }
        __syncthreads();
        float fre[16];
        #pragma unroll
        for (int cc = 0; cc < 16; ++cc) fre[cc] = featS[cc][nn];
        #pragma unroll
        for (int j = 0; j < 25; ++j)
            #pragma unroll
            for (int cc = 0; cc < 16; ++cc)
                acc[j] += fre[cc] * wS[dq + j][cc];
    }
    float* frow = f + (size_t)(n0 + nn) * DP + dq;
    #pragma unroll
    for (int j = 0; j < 25; ++j) frow[j] = acc[j] + b[dq + j];
}

// ---------------- kernel 2: build A, tiled+swizzled, vectorized stores ----------------
__global__ __launch_bounds__(256) void k_buildA(const float* __restrict__ f, const unsigned short* __restrict__ lut,
                                                f16_t* __restrict__ A) {
    __shared__ float fr[DP];
    int n = blockIdx.x;
    int t = threadIdx.x;
    if (t < DP) fr[t] = f[n * DP + t];
    __syncthreads();
    int r  = n & 127;
    int rsw = (r & 7) << 3;
    f16_t* tileBase = A + (size_t)(n >> 7) * KSTEPS * 8192;
    for (int g = t; g < KTOT / 8; g += 256) {
        int k0 = g * 8;
        u16x8 lu = *(const u16x8*)&lut[k0];
        f16x8 v;
        #pragma unroll
        for (int j = 0; j < 8; ++j) {
            int k = k0 + j;
            float x;
            if (k < KQ) {
                int d = lu[j] & 255, e = lu[j] >> 8;
                x = fr[d] * fr[e];
            } else if (k < KLIN) {
                x = fr[k - KQ];
            } else {
                x = 0.0f;
            }
            v[j] = (f16_t)x;
        }
        int kt = k0 >> 6, kin = k0 & 63;
        *(f16x8*)&tileBase[kt * 8192 + r * 64 + ((kin & 56) ^ rsw)] = v;
    }
}

// ---------------- kernel 3: build B, tiled+swizzled + const[l] ----------------
__global__ __launch_bounds__(256) void k_buildB(const float* __restrict__ icov, const float* __restrict__ mean,
                                                const unsigned short* __restrict__ lut,
                                                f16_t* __restrict__ Bm, float* __restrict__ constl) {
    __shared__ float ic[DP * 101];   // stride 101: conflict-free column reads
    __shared__ float ml[DP];
    __shared__ float wv[DP];
    __shared__ float part[DP];
    int l = blockIdx.x;
    int t = threadIdx.x;
    const float4* src4 = (const float4*)(icov + (size_t)l * DP * DP);
    for (int i4 = t; i4 < DP * DP / 4; i4 += 256) {
        float4 v = src4[i4];
        int flat = i4 * 4;
        int row = flat / 100;
        int col = flat - row * 100;   // 100 % 4 == 0: never crosses a row
        float* dst = &ic[row * 101 + col];
        dst[0] = v.x; dst[1] = v.y; dst[2] = v.z; dst[3] = v.w;
    }
    if (t < DP) ml[t] = mean[t * LNUM + l];
    __syncthreads();
    if (t < DP) {
        float icm = 0.f, ictm = 0.f;
        for (int e = 0; e < DP; ++e) {
            icm  += ic[t * 101 + e] * ml[e];
            ictm += ic[e * 101 + t] * ml[e];
        }
        wv[t]   = icm + ictm;        // (S m)_t  with S = IC + IC^T
        part[t] = ml[t] * icm;       // for m^T IC m
    }
    __syncthreads();
    if (t == 0) {
        float c = 0.f;
        for (int d = 0; d < DP; ++d) c += part[d];
        constl[l] = c;               // m^T IC m
    }
    int r  = l & 127;
    int rsw = (r & 7) << 3;
    f16_t* tileBase = Bm + (size_t)(l >> 7) * KSTEPS * 8192;
    for (int g = t; g < KTOT / 8; g += 256) {
        int k0 = g * 8;
        u16x8 lu = *(const u16x8*)&lut[k0];
        f16x8 v;
        #pragma unroll
        for (int j = 0; j < 8; ++j) {
            int k = k0 + j;
            float x;
            if (k < KQ) {
                int d = lu[j] & 255, e = lu[j] >> 8;
                float s = ic[d * 101 + e] + ic[e * 101 + d];
                x = (d == e) ? 0.5f * s : s;
            } else if (k < KLIN) {
                x = -wv[k - KQ];
            } else {
                x = 0.0f;
            }
            v[j] = (f16_t)x;
        }
        int kt = k0 >> 6, kin = k0 & 63;
        *(f16x8*)&tileBase[kt * 8192 + r * 64 + ((kin & 56) ^ rsw)] = v;
    }
}

// ---------------- kernel 4: 128^2 MFMA GEMM, dbuf + counted vmcnt + raw barriers ----------------
// True lookahead-1: stage(kt+1)->p^1 issued at top of kt; per-wave s_waitcnt vmcnt(8)
// waits only for stage(kt) (issued a full iteration ago); stage(kt+1)'s 8 loads stay in
// flight across both barriers. barrier-A: buffer p fully staged (every wave passed its
// own vmcnt). barrier-B: all reads of p done before next iter stages into p.
__global__ __launch_bounds__(256, 2) void k_gemm(const f16_t* __restrict__ A, const f16_t* __restrict__ Bm,
                                                 const float* __restrict__ constl, unsigned* __restrict__ mind) {
    __shared__ __align__(16) f16_t sA[2][8192];
    __shared__ __align__(16) f16_t sB[2][8192];

    int bid = blockIdx.x;
    int pid = ((bid & 7) << 7) | (bid >> 3);       // XCD swizzle (1024 % 8 == 0, bijective)
    int group = pid >> 8;
    int pin = pid & 255;
    int bm = group * 8 + (pin & 7);
    int bn = pin >> 3;

    int t = threadIdx.x;
    int lane = t & 63;
    int w = t >> 6;
    int wr = w >> 1, wc = w & 1;

    f32x4 acc[4][4];
    #pragma unroll
    for (int i = 0; i < 4; ++i)
        #pragma unroll
        for (int j = 0; j < 4; ++j) acc[i][j] = (f32x4){0.f, 0.f, 0.f, 0.f};

    const f16_t* Atile = A  + (size_t)bm * KSTEPS * 8192 + w * 2048 + lane * 8;
    const f16_t* Btile = Bm + (size_t)bn * KSTEPS * 8192 + w * 2048 + lane * 8;

    int l15 = lane & 15;
    int xorv = (lane & 7) << 3;
    int klobase = (lane >> 4) * 8;
    int arowbase = wr * 64 + l15;
    int browbase = wc * 64 + l15;

    // prologue: stage kt=0 into parity 0 (8 loads/wave outstanding)
    #pragma unroll
    for (int c = 0; c < 4; ++c) {
        gload_lds16(Atile + c * 512, &sA[0][w * 2048 + c * 512]);
        gload_lds16(Btile + c * 512, &sB[0][w * 2048 + c * 512]);
    }

    for (int kt = 0; kt < KSTEPS; ++kt) {
        int p = kt & 1;
        if (kt + 1 < KSTEPS) {
            const f16_t* As = Atile + (size_t)(kt + 1) * 8192;
            const f16_t* Bs = Btile + (size_t)(kt + 1) * 8192;
            #pragma unroll
            for (int c = 0; c < 4; ++c) {
                gload_lds16(As + c * 512, &sA[p ^ 1][w * 2048 + c * 512]);
                gload_lds16(Bs + c * 512, &sB[p ^ 1][w * 2048 + c * 512]);
            }
            asm volatile("s_waitcnt vmcnt(8)" ::: "memory");   // stage(kt) landed; kt+1 in flight
        } else {
            asm volatile("s_waitcnt vmcnt(0)" ::: "memory");   // final tile fully landed
        }
        __builtin_amdgcn_s_barrier();                          // barrier-A: p staged by all waves
        __builtin_amdgcn_sched_barrier(0);
        #pragma unroll
        for (int kk = 0; kk < 2; ++kk) {
            int klo = (kk * 32 + klobase) ^ xorv;
            f16x8 afr[4], bfr[4];
            #pragma unroll
            for (int mi = 0; mi < 4; ++mi)
                afr[mi] = *(const f16x8*)&sA[p][(arowbase + mi * 16) * 64 + klo];
            #pragma unroll
            for (int ni = 0; ni < 4; ++ni)
                bfr[ni] = *(const f16x8*)&sB[p][(browbase + ni * 16) * 64 + klo];
            #pragma unroll
            for (int mi = 0; mi < 4; ++mi)
                #pragma unroll
                for (int ni = 0; ni < 4; ++ni)
                    acc[mi][ni] = __builtin_amdgcn_mfma_f32_16x16x32_f16(afr[mi], bfr[ni], acc[mi][ni], 0, 0, 0);
        }
        __builtin_amdgcn_sched_barrier(0);
        __builtin_amdgcn_s_barrier();                          // barrier-B: reads of p done
        __builtin_amdgcn_sched_barrier(0);
    }

    // epilogue: dist = acc + const[col]; min over this block's cols per row; atomicMin
    int colbase = bn * 128 + wc * 64 + l15;
    float cl[4];
    #pragma unroll
    for (int ni = 0; ni < 4; ++ni) cl[ni] = constl[colbase + ni * 16];
    #pragma unroll
    for (int mi = 0; mi < 4; ++mi) {
        #pragma unroll
        for (int j = 0; j < 4; ++j) {
            float v = 1e30f;
            #pragma unroll
            for (int ni = 0; ni < 4; ++ni) v = fminf(v, acc[mi][ni][j] + cl[ni]);
            #pragma unroll
            for (int s = 1; s < 16; s <<= 1) v = fminf(v, __shfl_xor(v, s, 64));
            if (l15 == 0) {
                int row = bm * 128 + wr * 64 + mi * 16 + (lane >> 4) * 4 + j;
                atomicMin(&mind[row], f2u(v));
            }
        }
    }
}

// ---------------- kernel 5: global min/max of mind ----------------
__global__ void k_minmax(const unsigned* __restrict__ mind, float* __restrict__ gmm) {
    __shared__ float smin[256], smax[256];
    int t = threadIdx.x;
    float vmin = 1e30f, vmax = -1e30f;
    for (int i = t; i < NPIX; i += 256) {
        float v = u2f(mind[i]);
        vmin = fminf(vmin, v);
        vmax = fmaxf(vmax, v);
    }
    smin[t] = vmin; smax[t] = vmax;
    __syncthreads();
    for (int s = 128; s > 0; s >>= 1) {
        if (t < s) {
            smin[t] = fminf(smin[t], smin[t + s]);
            smax[t] = fmaxf(smax[t], smax[t + s]);
        }
        __syncthreads();
    }
    if (t == 0) { gmm[0] = smin[0]; gmm[1] = smax[0]; }
}

// ---------------- kernel 6: normalize + bilinear upsample 64->256 (float32 output) ----------------
__global__ void k_upsample(const unsigned* __restrict__ mind, const float* __restrict__ gmm,
                           float* __restrict__ out) {
    int gid = blockIdx.x * 256 + threadIdx.x;   // 65536
    int i = gid >> 8, j = gid & 255;
    float gmin = gmm[0];
    float scale = 1.0f / (gmm[1] - gmm[0] + 1e-8f);
    float x = fminf(fmaxf(j * 0.25f - 0.375f, 0.0f), 63.0f);
    float y = fminf(fmaxf(i * 0.25f - 0.375f, 0.0f), 63.0f);
    int x0 = (int)x, y0 = (int)y;
    int x1 = min(x0 + 1, 63), y1 = min(y0 + 1, 63);
    float fx = x - x0, fy = y - y0;
    float v00 = u2f(mind[y0 * 64 + x0]), v01 = u2f(mind[y0 * 64 + x1]);
    float v10 = u2f(mind[y1 * 64 + x0]), v11 = u2f(mind[y1 * 64 + x1]);
    float v = v00 * (1.f - fy) * (1.f - fx) + v01 * (1.f - fy) * fx
            + v10 * fy * (1.f - fx) + v11 * fy * fx;
    out[gid] = (v - gmin) * scale;
}

// ---------------- diagnostic: ws too small -> uniform 0.25 output (absmax ~0.70) ----------------
__global__ void k_diag(float* __restrict__ out) {
    int gid = blockIdx.x * 256 + threadIdx.x;
    out[gid] = 0.25f;
}

extern "C" void kernel_launch(void* const* d_in, const int* in_sizes, int n_in,
                              void* d_out, int out_size, void* d_ws, size_t ws_size,
                              hipStream_t stream) {
    const float* feat = (const float*)d_in[0];
    const float* pw   = (const float*)d_in[1];
    const float* pb   = (const float*)d_in[2];
    const float* mean = (const float*)d_in[3];
    const float* icov = (const float*)d_in[4];

    size_t need = 0;
    auto count = [&need](size_t bytes) { need = ((need + 255) & ~(size_t)255) + bytes; };
    count((size_t)NPIX * DP * 4);
    count((size_t)NPIX * KTOT * 2);
    count((size_t)LNUM * KTOT * 2);
    count((size_t)LNUM * 4);
    count((size_t)NPIX * 4);
    count(2 * 4);
    count((size_t)KTOT * 2);
    if (ws_size < need) {
        k_diag<<<256, 256, 0, stream>>>((float*)d_out);
        return;
    }

    char* ws = (char*)d_ws;
    size_t off = 0;
    auto alloc = [&](size_t bytes) -> void* {
        off = (off + 255) & ~(size_t)255;
        void* p = ws + off;
        off += bytes;
        return p;
    };
    float*          f      = (float*)alloc((size_t)NPIX * DP * 4);
    f16_t*          Amat   = (f16_t*)alloc((size_t)NPIX * KTOT * 2);
    f16_t*          Bmat   = (f16_t*)alloc((size_t)LNUM * KTOT * 2);
    float*          constl = (float*)alloc((size_t)LNUM * 4);
    unsigned*       mind   = (unsigned*)alloc((size_t)NPIX * 4);
    float*          gmm    = (float*)alloc(2 * 4);
    unsigned short* lut    = (unsigned short*)alloc((size_t)KTOT * 2);

    k_lut     <<<(KTOT + 255) / 256, 256, 0, stream>>>(lut, mind);
    k_proj    <<<64, 256, 0, stream>>>(feat, pw, pb, f);
    k_buildA  <<<NPIX, 256, 0, stream>>>(f, lut, Amat);
    k_buildB  <<<LNUM, 256, 0, stream>>>(icov, mean, lut, Bmat, constl);
    k_gemm    <<<1024, 256, 0, stream>>>(Amat, Bmat, constl, mind);
    k_minmax  <<<1, 256, 0, stream>>>(mind, gmm);
    k_upsample<<<256, 256, 0, stream>>>(mind, gmm, (float*)d_out);
}

// Round 9
// 297.652 us; speedup vs baseline: 1.3348x; 1.3348x over previous
//
#include <hip/hip_runtime.h>
#include <hip/hip_bf16.h>
#include <stdint.h>

#define CIN   448
#define DP    100
#define NPIX  4096
#define LNUM  4096
#define KQ    5050      // packed upper-triangle columns
#define KLIN  5150      // + 100 linear columns
#define KTOT  5184      // padded to 81*64
#define KSTEPS (KTOT / 64)
#define OUTHW 256

typedef _Float16 f16_t;
typedef _Float16 f16x8 __attribute__((ext_vector_type(8)));
typedef float    f32x4 __attribute__((ext_vector_type(4)));
typedef unsigned short u16x8 __attribute__((ext_vector_type(8)));

static __device__ __forceinline__ int tri_off(int d) { return (d * (201 - d)) >> 1; }

static __device__ __forceinline__ void unpack_tri(int k, int& d, int& e) {
    int dd = (int)((201.0f - sqrtf(40401.0f - 8.0f * (float)k)) * 0.5f);
    if (dd < 0) dd = 0;
    if (dd > 99) dd = 99;
    while (tri_off(dd + 1) <= k) ++dd;
    while (tri_off(dd) > k) --dd;
    d = dd;
    e = dd + (k - tri_off(dd));
}

static __device__ __forceinline__ unsigned f2u(float x) {
    unsigned b = __float_as_uint(x);
    return (b & 0x80000000u) ? ~b : (b | 0x80000000u);
}
static __device__ __forceinline__ float u2f(unsigned u) {
    unsigned b = (u & 0x80000000u) ? (u & 0x7FFFFFFFu) : ~u;
    return __uint_as_float(b);
}

static __device__ __forceinline__ void gload_lds16(const f16_t* g, f16_t* l) {
    __builtin_amdgcn_global_load_lds((const __attribute__((address_space(1))) unsigned*)g,
                                     (__attribute__((address_space(3))) unsigned*)l,
                                     16, 0, 0);
}

// ---------------- kernel 0: tri-unpack LUT + init per-row min ----------------
__global__ void k_lut(unsigned short* __restrict__ lut, unsigned* __restrict__ mind) {
    int k = blockIdx.x * 256 + threadIdx.x;
    if (k < KTOT) {
        int d = 0, e = 0;
        if (k < KQ) unpack_tri(k, d, e);
        lut[k] = (unsigned short)(d | (e << 8));
    }
    if (k < NPIX) mind[k] = 0xFFFFFFFFu;
}

// ---------------- kernel 1: projection f[n,d] = feat[:,n] . w[d,:] + b[d] ----------------
// (r4 version: 1600 blocks, L2-bound ~22us; r8's LDS-tiled rework regressed badly)
__global__ void k_proj(const float* __restrict__ feat, const float* __restrict__ w,
                       const float* __restrict__ b, float* __restrict__ f) {
    int gid = blockIdx.x * 256 + threadIdx.x;   // 409600 = 4096*100
    int n = gid & 4095;
    int d = gid >> 12;
    float acc = b[d];
    const float* wd = w + d * CIN;
    #pragma unroll 4
    for (int c = 0; c < CIN; ++c) acc += feat[c * 4096 + n] * wd[c];
    f[n * DP + d] = acc;
}

// ---------------- kernel 2: build A, tiled+swizzled, vectorized stores ----------------
__global__ __launch_bounds__(256) void k_buildA(const float* __restrict__ f, const unsigned short* __restrict__ lut,
                                                f16_t* __restrict__ A) {
    __shared__ float fr[DP];
    int n = blockIdx.x;
    int t = threadIdx.x;
    if (t < DP) fr[t] = f[n * DP + t];
    __syncthreads();
    int r  = n & 127;
    int rsw = (r & 7) << 3;
    f16_t* tileBase = A + (size_t)(n >> 7) * KSTEPS * 8192;
    for (int g = t; g < KTOT / 8; g += 256) {
        int k0 = g * 8;
        u16x8 lu = *(const u16x8*)&lut[k0];
        f16x8 v;
        #pragma unroll
        for (int j = 0; j < 8; ++j) {
            int k = k0 + j;
            float x;
            if (k < KQ) {
                int d = lu[j] & 255, e = lu[j] >> 8;
                x = fr[d] * fr[e];
            } else if (k < KLIN) {
                x = fr[k - KQ];
            } else {
                x = 0.0f;
            }
            v[j] = (f16_t)x;
        }
        int kt = k0 >> 6, kin = k0 & 63;
        *(f16x8*)&tileBase[kt * 8192 + r * 64 + ((kin & 56) ^ rsw)] = v;
    }
}

// ---------------- kernel 3: build B, tiled+swizzled + const[l] ----------------
__global__ __launch_bounds__(256) void k_buildB(const float* __restrict__ icov, const float* __restrict__ mean,
                                                const unsigned short* __restrict__ lut,
                                                f16_t* __restrict__ Bm, float* __restrict__ constl) {
    __shared__ float ic[DP * 101];   // stride 101: conflict-free column reads
    __shared__ float ml[DP];
    __shared__ float wv[DP];
    __shared__ float part[DP];
    int l = blockIdx.x;
    int t = threadIdx.x;
    const float4* src4 = (const float4*)(icov + (size_t)l * DP * DP);
    for (int i4 = t; i4 < DP * DP / 4; i4 += 256) {
        float4 v = src4[i4];
        int flat = i4 * 4;
        int row = flat / 100;
        int col = flat - row * 100;   // 100 % 4 == 0: never crosses a row
        float* dst = &ic[row * 101 + col];
        dst[0] = v.x; dst[1] = v.y; dst[2] = v.z; dst[3] = v.w;
    }
    if (t < DP) ml[t] = mean[t * LNUM + l];
    __syncthreads();
    if (t < DP) {
        float icm = 0.f, ictm = 0.f;
        for (int e = 0; e < DP; ++e) {
            icm  += ic[t * 101 + e] * ml[e];
            ictm += ic[e * 101 + t] * ml[e];
        }
        wv[t]   = icm + ictm;        // (S m)_t  with S = IC + IC^T
        part[t] = ml[t] * icm;       // for m^T IC m
    }
    __syncthreads();
    if (t == 0) {
        float c = 0.f;
        for (int d = 0; d < DP; ++d) c += part[d];
        constl[l] = c;               // m^T IC m
    }
    int r  = l & 127;
    int rsw = (r & 7) << 3;
    f16_t* tileBase = Bm + (size_t)(l >> 7) * KSTEPS * 8192;
    for (int g = t; g < KTOT / 8; g += 256) {
        int k0 = g * 8;
        u16x8 lu = *(const u16x8*)&lut[k0];
        f16x8 v;
        #pragma unroll
        for (int j = 0; j < 8; ++j) {
            int k = k0 + j;
            float x;
            if (k < KQ) {
                int d = lu[j] & 255, e = lu[j] >> 8;
                float s = ic[d * 101 + e] + ic[e * 101 + d];
                x = (d == e) ? 0.5f * s : s;
            } else if (k < KLIN) {
                x = -wv[k - KQ];
            } else {
                x = 0.0f;
            }
            v[j] = (f16_t)x;
        }
        int kt = k0 >> 6, kin = k0 & 63;
        *(f16x8*)&tileBase[kt * 8192 + r * 64 + ((kin & 56) ^ rsw)] = v;
    }
}

// ---------------- kernel 4: MFMA GEMM — exact r5 structure (best measured: 164us, 1058 TF) ----------------
// 128^2 tile, 32KB LDS single buffer, global_load_lds(16B) into linear LDS (pre-swizzled
// global tiles), 2-barrier K-loop, fused row-min epilogue. Schedule grafts (r6-r8) all
// regressed: 2-phase counted-vmcnt is regime-gated null (guide T3/T4), occupancy is the
// binding latency-hider here (35% = ~2.8 blocks/CU of cross-block MFMA overlap).
__global__ __launch_bounds__(256, 2) void k_gemm(const f16_t* __restrict__ A, const f16_t* __restrict__ Bm,
                                                 const float* __restrict__ constl, unsigned* __restrict__ mind) {
    __shared__ __align__(16) f16_t sA[8192];
    __shared__ __align__(16) f16_t sB[8192];

    int bid = blockIdx.x;
    int pid = ((bid & 7) << 7) | (bid >> 3);       // XCD swizzle (1024 % 8 == 0, bijective)
    int group = pid >> 8;
    int pin = pid & 255;
    int bm = group * 8 + (pin & 7);
    int bn = pin >> 3;

    int t = threadIdx.x;
    int lane = t & 63;
    int w = t >> 6;
    int wr = w >> 1, wc = w & 1;

    f32x4 acc[4][4];
    #pragma unroll
    for (int i = 0; i < 4; ++i)
        #pragma unroll
        for (int j = 0; j < 4; ++j) acc[i][j] = (f32x4){0.f, 0.f, 0.f, 0.f};

    const f16_t* Atile = A + (size_t)bm * KSTEPS * 8192;
    const f16_t* Btile = Bm + (size_t)bn * KSTEPS * 8192;

    int chunk0 = w * 2048;           // f16 offset of this wave's 4KB region
    int lofs = lane * 8;             // f16 offset of this lane's 16B within a 1KB chunk

    int arow[4], brow[4];
    #pragma unroll
    for (int i = 0; i < 4; ++i) {
        arow[i] = wr * 64 + i * 16 + (lane & 15);
        brow[i] = wc * 64 + i * 16 + (lane & 15);
    }

    for (int kt = 0; kt < KSTEPS; ++kt) {
        const f16_t* As = Atile + kt * 8192;
        const f16_t* Bs = Btile + kt * 8192;
        #pragma unroll
        for (int c = 0; c < 4; ++c) {
            gload_lds16(As + chunk0 + c * 512 + lofs, &sA[chunk0 + c * 512]);
            gload_lds16(Bs + chunk0 + c * 512 + lofs, &sB[chunk0 + c * 512]);
        }
        __syncthreads();   // vmcnt drain + barrier: tile ready
        #pragma unroll
        for (int kk = 0; kk < 2; ++kk) {
            f16x8 afr[4], bfr[4];
            int klo = kk * 32 + (lane >> 4) * 8;   // multiple of 8, 0..56
            #pragma unroll
            for (int mi = 0; mi < 4; ++mi)
                afr[mi] = *(const f16x8*)&sA[arow[mi] * 64 + (klo ^ ((arow[mi] & 7) << 3))];
            #pragma unroll
            for (int ni = 0; ni < 4; ++ni)
                bfr[ni] = *(const f16x8*)&sB[brow[ni] * 64 + (klo ^ ((brow[ni] & 7) << 3))];
            #pragma unroll
            for (int mi = 0; mi < 4; ++mi)
                #pragma unroll
                for (int ni = 0; ni < 4; ++ni)
                    acc[mi][ni] = __builtin_amdgcn_mfma_f32_16x16x32_f16(afr[mi], bfr[ni], acc[mi][ni], 0, 0, 0);
        }
        __syncthreads();   // all MFMA fragment reads done before next stage overwrites
    }

    // epilogue: dist = acc + const[col]; min over this block's cols per row; atomicMin
    int colbase = bn * 128 + wc * 64 + (lane & 15);
    float cl[4];
    #pragma unroll
    for (int ni = 0; ni < 4; ++ni) cl[ni] = constl[colbase + ni * 16];
    #pragma unroll
    for (int mi = 0; mi < 4; ++mi) {
        #pragma unroll
        for (int j = 0; j < 4; ++j) {
            float v = 1e30f;
            #pragma unroll
            for (int ni = 0; ni < 4; ++ni) v = fminf(v, acc[mi][ni][j] + cl[ni]);
            #pragma unroll
            for (int s = 1; s < 16; s <<= 1) v = fminf(v, __shfl_xor(v, s, 64));
            if ((lane & 15) == 0) {
                int row = bm * 128 + wr * 64 + mi * 16 + (lane >> 4) * 4 + j;
                atomicMin(&mind[row], f2u(v));
            }
        }
    }
}

// ---------------- kernel 5: global min/max of mind ----------------
__global__ void k_minmax(const unsigned* __restrict__ mind, float* __restrict__ gmm) {
    __shared__ float smin[256], smax[256];
    int t = threadIdx.x;
    float vmin = 1e30f, vmax = -1e30f;
    for (int i = t; i < NPIX; i += 256) {
        float v = u2f(mind[i]);
        vmin = fminf(vmin, v);
        vmax = fmaxf(vmax, v);
    }
    smin[t] = vmin; smax[t] = vmax;
    __syncthreads();
    for (int s = 128; s > 0; s >>= 1) {
        if (t < s) {
            smin[t] = fminf(smin[t], smin[t + s]);
            smax[t] = fmaxf(smax[t], smax[t + s]);
        }
        __syncthreads();
    }
    if (t == 0) { gmm[0] = smin[0]; gmm[1] = smax[0]; }
}

// ---------------- kernel 6: normalize + bilinear upsample 64->256 (float32 output) ----------------
__global__ void k_upsample(const unsigned* __restrict__ mind, const float* __restrict__ gmm,
                           float* __restrict__ out) {
    int gid = blockIdx.x * 256 + threadIdx.x;   // 65536
    int i = gid >> 8, j = gid & 255;
    float gmin = gmm[0];
    float scale = 1.0f / (gmm[1] - gmm[0] + 1e-8f);
    float x = fminf(fmaxf(j * 0.25f - 0.375f, 0.0f), 63.0f);
    float y = fminf(fmaxf(i * 0.25f - 0.375f, 0.0f), 63.0f);
    int x0 = (int)x, y0 = (int)y;
    int x1 = min(x0 + 1, 63), y1 = min(y0 + 1, 63);
    float fx = x - x0, fy = y - y0;
    float v00 = u2f(mind[y0 * 64 + x0]), v01 = u2f(mind[y0 * 64 + x1]);
    float v10 = u2f(mind[y1 * 64 + x0]), v11 = u2f(mind[y1 * 64 + x1]);
    float v = v00 * (1.f - fy) * (1.f - fx) + v01 * (1.f - fy) * fx
            + v10 * fy * (1.f - fx) + v11 * fy * fx;
    out[gid] = (v - gmin) * scale;
}

// ---------------- diagnostic: ws too small -> uniform 0.25 output (absmax ~0.70) ----------------
__global__ void k_diag(float* __restrict__ out) {
    int gid = blockIdx.x * 256 + threadIdx.x;
    out[gid] = 0.25f;
}

extern "C" void kernel_launch(void* const* d_in, const int* in_sizes, int n_in,
                              void* d_out, int out_size, void* d_ws, size_t ws_size,
                              hipStream_t stream) {
    const float* feat = (const float*)d_in[0];
    const float* pw   = (const float*)d_in[1];
    const float* pb   = (const float*)d_in[2];
    const float* mean = (const float*)d_in[3];
    const float* icov = (const float*)d_in[4];

    size_t need = 0;
    auto count = [&need](size_t bytes) { need = ((need + 255) & ~(size_t)255) + bytes; };
    count((size_t)NPIX * DP * 4);
    count((size_t)NPIX * KTOT * 2);
    count((size_t)LNUM * KTOT * 2);
    count((size_t)LNUM * 4);
    count((size_t)NPIX * 4);
    count(2 * 4);
    count((size_t)KTOT * 2);
    if (ws_size < need) {
        k_diag<<<256, 256, 0, stream>>>((float*)d_out);
        return;
    }

    char* ws = (char*)d_ws;
    size_t off = 0;
    auto alloc = [&](size_t bytes) -> void* {
        off = (off + 255) & ~(size_t)255;
        void* p = ws + off;
        off += bytes;
        return p;
    };
    float*          f      = (float*)alloc((size_t)NPIX * DP * 4);
    f16_t*          Amat   = (f16_t*)alloc((size_t)NPIX * KTOT * 2);
    f16_t*          Bmat   = (f16_t*)alloc((size_t)LNUM * KTOT * 2);
    float*          constl = (float*)alloc((size_t)LNUM * 4);
    unsigned*       mind   = (unsigned*)alloc((size_t)NPIX * 4);
    float*          gmm    = (float*)alloc(2 * 4);
    unsigned short* lut    = (unsigned short*)alloc((size_t)KTOT * 2);

    k_lut     <<<(KTOT + 255) / 256, 256, 0, stream>>>(lut, mind);
    k_proj    <<<1600, 256, 0, stream>>>(feat, pw, pb, f);
    k_buildA  <<<NPIX, 256, 0, stream>>>(f, lut, Amat);
    k_buildB  <<<LNUM, 256, 0, stream>>>(icov, mean, lut, Bmat, constl);
    k_gemm    <<<1024, 256, 0, stream>>>(Amat, Bmat, constl, mind);
    k_minmax  <<<1, 256, 0, stream>>>(mind, gmm);
    k_upsample<<<256, 256, 0, stream>>>(mind, gmm, (float*)d_out);
}